// Round 13
// baseline (242.664 us; speedup 1.0000x reference)
//
#include <hip/hip_runtime.h>
#include <stdint.h>

// Problem constants
#define B_   16
#define N_   4096
#define S_   1024
#define K_   32
#define CIN_ 64
#define P_   524288      // B*S*K points through the MLP
#define PQ_  16384       // B*S queries
#define EPS_ 1e-5f

// Workspace layout (bytes)
#define SZ_IDX    ((size_t)P_ * 4)            // knn indices, int32
#define SZ_Y      ((size_t)P_ * 64 * 2)       // 64ch x P bf16 (subtiled units)
#define SZ_MX     ((size_t)PQ_ * 128 * 4)     // per-(q,ch) f32
#define OFF_IDX   ((size_t)0)
#define OFF_Y0    (OFF_IDX + SZ_IDX)
#define OFF_Y1    (OFF_Y0 + SZ_Y)
#define OFF_MX    (OFF_Y1 + SZ_Y)
#define OFF_MN    (OFF_MX + SZ_MX)
#define OFF_STATS (OFF_MN + SZ_MX)            // 8 replicas x 512 f32 (16 KB, zeroed)
#define OFF_FIN   (OFF_STATS + 16384)         // 512 f32 finalized scale/shift
#define OFF_FPSC  (OFF_FIN + 2048)            // canonical fps, 16384 int32
#define OFF_PXYZW (OFF_FPSC + (size_t)PQ_ * 4)  // B*N float4 (x,y,z,|x|^2)
#define WS_NEEDED (OFF_PXYZW + (size_t)B_ * N_ * 16)

typedef unsigned short u16;
typedef short bfrag __attribute__((ext_vector_type(8)));   // 8 bf16 (4 VGPRs)
typedef float f32x4 __attribute__((ext_vector_type(4)));

__device__ __forceinline__ float b2f(unsigned v) {
  return __uint_as_float((v & 0xffffu) << 16);
}
__device__ __forceinline__ u16 f2b(float f) {
  unsigned u = __float_as_uint(f);
  unsigned r = (u + 0x7fffu + ((u >> 16) & 1u)) >> 16;  // RNE
  return (u16)r;
}
__device__ __forceinline__ unsigned pk2(float a, float b) {
  return (unsigned)f2b(a) | ((unsigned)f2b(b) << 16);
}

// ---------------------------------------------------------------------------
// fps canonicalization (int64 vs int32 storage) -> int32, clamped.
// ---------------------------------------------------------------------------
__global__ __launch_bounds__(256) void fps_canon_kernel(
    const int* __restrict__ fpsraw, int* __restrict__ fpsc)
{
  __shared__ int is64;
  const int tid = threadIdx.x;
  if (tid == 0) is64 = 1;
  __syncthreads();
  if (tid < 64) {
    if (fpsraw[2 * tid + 1] != 0) atomicAnd(&is64, 0);
  }
  __syncthreads();
  int i = blockIdx.x * 256 + tid;
  if (i < PQ_) {
    int src = is64 ? (2 * i) : i;
    int v = fpsraw[src];
    fpsc[i] = (v & 0xFFF);
  }
}

// ---------------------------------------------------------------------------
// prep: pack (x, y, z, |x|^2) per point. |x|^2 uses the EXACT reference
// op ordering ((x0*x0 + x1*x1) + x2*x2), f32, no FMA.
// ---------------------------------------------------------------------------
__global__ __launch_bounds__(256) void prep_kernel(
    const float* __restrict__ xyz, float4* __restrict__ pxyzw)
{
  int i = blockIdx.x * 256 + threadIdx.x;   // 0 .. B*N-1
  float x0 = xyz[i*3+0], x1 = xyz[i*3+1], x2 = xyz[i*3+2];
  float s2 = __fadd_rn(__fadd_rn(__fmul_rn(x0,x0), __fmul_rn(x1,x1)), __fmul_rn(x2,x2));
  pxyzw[i] = make_float4(x0, x1, x2, s2);
}

// ---------------------------------------------------------------------------
// KNN v7: 2 queries per block (shared point stream -> half the L2 traffic).
// - packed 2-bins-per-u32 histograms (counts <= 4096: no cross-half carry)
// - bin cache in registers only (no distance cache); candidate distances
//   (~1-8/query) recomputed bit-identically from one extra load
// - scan + refine run concurrently on waves 0/1 (one per query)
// ---------------------------------------------------------------------------
#define NBIN 2048
#define CAND_CAP 512

__global__ __launch_bounds__(256) void knn_kernel(
    const float4* __restrict__ pxyzw, const int* __restrict__ fps,
    int* __restrict__ idxout, float* __restrict__ out_xyz)
{
  __shared__ unsigned histp[2][NBIN/2];   // packed: 2 bins per u32, 8 KB
  __shared__ float cd[2][CAND_CAP];       // 4 KB
  __shared__ int   ci_[2][CAND_CAP];      // 4 KB
  __shared__ int   sel[2][K_];
  __shared__ int   sCnt[2], sCand[2], sT[2];

  const int q0  = blockIdx.x * 2;
  const int b   = q0 >> 10;
  const int tid = threadIdx.x;
  const float4* xb4 = pxyzw + (size_t)b * N_;
  const int ctr0 = fps[q0]     & 0xFFF;
  const int ctr1 = fps[q0 + 1] & 0xFFF;
  const float4 c0 = xb4[ctr0];
  const float4 c1 = xb4[ctr1];

  if (tid < 2) {
    const float4 cc = tid ? c1 : c0;
    out_xyz[(size_t)(q0 + tid)*3+0] = cc.x;
    out_xyz[(size_t)(q0 + tid)*3+1] = cc.y;
    out_xyz[(size_t)(q0 + tid)*3+2] = cc.z;
    sCnt[tid] = 0; sCand[tid] = 0;
  }
  {
    uint4* hz = (uint4*)&histp[0][0];
    hz[tid] = make_uint4(0,0,0,0);        // 256*16B = 4 KB
    hz[tid + 256] = make_uint4(0,0,0,0);  // total 8 KB
  }
  __syncthreads();

  // pass 1: distances -> bins (packed registers) + packed histograms.
  // (int) truncation handles tiny-negative d (bin 0), upper clamp only.
  unsigned bpk0[8], bpk1[8];
  #pragma unroll
  for (int it = 0; it < 16; ++it) {
    int n = it * 256 + tid;
    float4 v = xb4[n];
    float dt0 = __fadd_rn(__fadd_rn(__fmul_rn(c0.x,v.x), __fmul_rn(c0.y,v.y)), __fmul_rn(c0.z,v.z));
    float d0  = __fsub_rn(__fadd_rn(c0.w, v.w), __fmul_rn(2.0f, dt0));
    float dt1 = __fadd_rn(__fadd_rn(__fmul_rn(c1.x,v.x), __fmul_rn(c1.y,v.y)), __fmul_rn(c1.z,v.z));
    float d1  = __fsub_rn(__fadd_rn(c1.w, v.w), __fmul_rn(2.0f, dt1));
    int b0 = (int)(d0 * 128.0f);
    b0 = b0 > (NBIN-1) ? (NBIN-1) : b0; b0 = b0 < 0 ? 0 : b0;
    int b1 = (int)(d1 * 128.0f);
    b1 = b1 > (NBIN-1) ? (NBIN-1) : b1; b1 = b1 < 0 ? 0 : b1;
    if (it & 1) { bpk0[it >> 1] |= (unsigned)b0 << 16; bpk1[it >> 1] |= (unsigned)b1 << 16; }
    else        { bpk0[it >> 1]  = (unsigned)b0;       bpk1[it >> 1]  = (unsigned)b1; }
    atomicAdd(&histp[0][b0 >> 1], (b0 & 1) ? 0x10000u : 1u);
    atomicAdd(&histp[1][b1 >> 1], (b1 & 1) ? 0x10000u : 1u);
  }
  __syncthreads();

  // scan: wave w (w<2) finds T for query w, 64 bins at a time
  const int lane = tid & 63, wid = tid >> 6;
  if (wid < 2) {
    const unsigned* hq = &histp[wid][0];
    int cum = 0, base = 0, found = 0;
    while (!found && base < NBIN) {
      int bn = base + lane;
      int h = (int)((hq[bn >> 1] >> ((bn & 1) * 16)) & 0xFFFFu);
      int pre = h;
      #pragma unroll
      for (int off = 1; off < 64; off <<= 1) {
        int v = __shfl_up(pre, off, 64);
        if (lane >= off) pre += v;
      }
      int tot = __shfl(pre, 63, 64);
      bool cross = (cum + pre >= K_) && (cum + pre - h < K_);
      unsigned long long mm = __ballot(cross);
      if (mm) {
        if (lane == 0) sT[wid] = base + (int)(__ffsll((long long)mm) - 1);
        found = 1;
      }
      cum += tot;
      base += 64;
    }
  }
  __syncthreads();
  const int T0 = sT[0], T1 = sT[1];

  // pass 2: rare hits -> plain LDS atomics; candidate d recomputed (exact)
  #pragma unroll
  for (int it = 0; it < 16; ++it) {
    int b0 = (int)((bpk0[it >> 1] >> ((it & 1) * 16)) & 0xFFFFu);
    if (b0 <= T0) {
      int n = it * 256 + tid;
      if (b0 < T0) {
        int s = atomicAdd(&sCnt[0], 1);
        if (s < K_) sel[0][s] = n;
      } else {
        int s = atomicAdd(&sCand[0], 1);
        if (s < CAND_CAP) {
          float4 v = xb4[n];
          float dt = __fadd_rn(__fadd_rn(__fmul_rn(c0.x,v.x), __fmul_rn(c0.y,v.y)), __fmul_rn(c0.z,v.z));
          float d  = __fsub_rn(__fadd_rn(c0.w, v.w), __fmul_rn(2.0f, dt));
          cd[0][s] = d; ci_[0][s] = n;
        }
      }
    }
    int b1 = (int)((bpk1[it >> 1] >> ((it & 1) * 16)) & 0xFFFFu);
    if (b1 <= T1) {
      int n = it * 256 + tid;
      if (b1 < T1) {
        int s = atomicAdd(&sCnt[1], 1);
        if (s < K_) sel[1][s] = n;
      } else {
        int s = atomicAdd(&sCand[1], 1);
        if (s < CAND_CAP) {
          float4 v = xb4[n];
          float dt = __fadd_rn(__fadd_rn(__fmul_rn(c1.x,v.x), __fmul_rn(c1.y,v.y)), __fmul_rn(c1.z,v.z));
          float d  = __fsub_rn(__fadd_rn(c1.w, v.w), __fmul_rn(2.0f, dt));
          cd[1][s] = d; ci_[1][s] = n;
        }
      }
    }
  }
  __syncthreads();

  // refine: wave w (w<2) refines query w; wave-private, no block barriers
  if (wid < 2) {
    int m = sCnt[wid]; m = m > K_ ? K_ : m;
    int cc = sCand[wid]; cc = cc > CAND_CAP ? CAND_CAP : cc;
    const int r = K_ - m;
    float* cdq = &cd[wid][0];
    int* ciq = &ci_[wid][0];
    for (int it = 0; it < r; ++it) {
      float bd = 3.0e38f; int bi = 0x7fffffff;
      for (int j = lane; j < cc; j += 64) {
        float dv = cdq[j]; int iv = ciq[j];
        if (dv < bd || (dv == bd && iv < bi)) { bd = dv; bi = iv; }
      }
      #pragma unroll
      for (int off = 32; off > 0; off >>= 1) {
        float od = __shfl_down(bd, off, 64);
        int   oi = __shfl_down(bi, off, 64);
        if (od < bd || (od == bd && oi < bi)) { bd = od; bi = oi; }
      }
      int win = __shfl(bi, 0, 64);
      if (lane == 0) sel[wid][m + it] = win & 0xFFF;
      for (int j = lane; j < cc; j += 64) if (ciq[j] == win) cdq[j] = 3.0e38f;
    }
  }
  __syncthreads();
  if (tid < 2 * K_) {
    int qq = tid >> 5, kk = tid & 31;
    idxout[(size_t)(q0 + qq) * K_ + kk] = sel[qq][kk] & 0xFFF;
  }
}

// ===========================================================================
// MFMA MLP layers (unchanged). Fragment mapping (m89/m91):
//   A(M=16,K=32): lane holds A[row=lane&15][k=(lane>>4)*8+i]
//   B(K=32,N=16): lane holds B[k=(lane>>4)*8+i][col=lane&15]
//   D(M=16,N=16): lane holds D[row=(lane>>4)*4+j][col=lane&15]
// Paired 16B Y stores via shfl_xor(16); 8 per-XCD stats replicas.
// ===========================================================================

__global__ __launch_bounds__(256) void l0_mfma(
    const float* __restrict__ xyz, const float* __restrict__ feat,
    const int* __restrict__ fps, const int* __restrict__ idxin,
    const float* __restrict__ W0, const float* __restrict__ b0,
    uint4* __restrict__ Y0g, float* __restrict__ sumg, float* __restrict__ sqg)
{
  __shared__ uint4 Wl[12*64];      // 12 KB
  __shared__ float bl[64];
  __shared__ float ssum[64], ssq[64];

  const int tid = threadIdx.x;
  const int bid0 = blockIdx.x;
  const int rep = (bid0 & 7) << 9;
  const int bid = (bid0 & 7) * ((int)gridDim.x >> 3) + (bid0 >> 3);
  const int pbase = bid * 128;
  const int q0 = bid * 4;
  const int b = bid >> 8;

  if (tid < 64) { bl[tid] = b0 ? b0[tid] : 0.f; ssum[tid] = 0.f; ssq[tid] = 0.f; }
  for (int u = tid; u < 12*64; u += 256) {
    int kc = u >> 6, o = u & 63;
    unsigned pk[4];
    #pragma unroll
    for (int hh = 0; hh < 4; ++hh) {
      int c0 = kc*8 + hh*2, c1 = c0 + 1;
      float v0 = (c0 < 64) ? W0[o*67 + 3 + c0] : (c0 < 67 ? W0[o*67 + (c0-64)] : 0.f);
      float v1 = (c1 < 64) ? W0[o*67 + 3 + c1] : (c1 < 67 ? W0[o*67 + (c1-64)] : 0.f);
      pk[hh] = pk2(v0, v1);
    }
    Wl[u] = make_uint4(pk[0], pk[1], pk[2], pk[3]);
  }

  const int lane = tid & 63, w = tid >> 6, g = lane >> 4, fr = lane & 15;
  const float* xb = xyz + (size_t)b * N_ * 3;
  const float* fbase = feat + (size_t)b * N_ * 64;

  int pidx[2];
  const int ct = fps[q0 + w] & 0xFFF;
  #pragma unroll
  for (int pm = 0; pm < 2; ++pm)
    pidx[pm] = idxin[pbase + w*32 + pm*16 + fr] & 0xFFF;

  bfrag xv[3][2];
  #pragma unroll
  for (int kk = 0; kk < 3; ++kk) {
    const int kc = kk*4 + g;
    #pragma unroll
    for (int pm = 0; pm < 2; ++pm) {
      uint4 uu;
      if (kc < 8) {
        const float* fp = fbase + pidx[pm]*64 + kc*8;
        float4 fa = *(const float4*)fp;
        float4 fb2 = *(const float4*)(fp + 4);
        uu = make_uint4(pk2(fa.x, fa.y), pk2(fa.z, fa.w),
                        pk2(fb2.x, fb2.y), pk2(fb2.z, fb2.w));
      } else if (kc == 8) {
        int n = pidx[pm];
        float dx = xb[n*3+0] - xb[ct*3+0];
        float dy = xb[n*3+1] - xb[ct*3+1];
        float dz = xb[n*3+2] - xb[ct*3+2];
        uu = make_uint4(pk2(dx, dy), (unsigned)f2b(dz), 0u, 0u);
      } else {
        uu = make_uint4(0u, 0u, 0u, 0u);
      }
      xv[kk][pm] = *(bfrag*)&uu;
    }
  }
  __syncthreads();

  f32x4 acc[4][2];
  #pragma unroll
  for (int m = 0; m < 4; ++m)
    #pragma unroll
    for (int j = 0; j < 4; ++j) {
      float v = bl[m*16 + g*4 + j];
      acc[m][0][j] = v; acc[m][1][j] = v;
    }
  #pragma unroll
  for (int kk = 0; kk < 3; ++kk) {
    const int kc = kk*4 + g;
    bfrag a[4];
    #pragma unroll
    for (int m = 0; m < 4; ++m) { uint4 u = Wl[kc*64 + m*16 + fr]; a[m] = *(bfrag*)&u; }
    #pragma unroll
    for (int m = 0; m < 4; ++m)
      #pragma unroll
      for (int pm = 0; pm < 2; ++pm)
        acc[m][pm] = __builtin_amdgcn_mfma_f32_16x16x32_bf16(a[m], xv[kk][pm], acc[m][pm], 0, 0, 0);
  }

  #pragma unroll
  for (int m = 0; m < 4; ++m) {
    #pragma unroll
    for (int j = 0; j < 4; ++j) {
      float v0 = acc[m][0][j], v1 = acc[m][1][j];
      float s = v0 + v1, s2 = v0*v0 + v1*v1;
      #pragma unroll
      for (int d = 1; d < 16; d <<= 1) { s += __shfl_xor(s, d); s2 += __shfl_xor(s2, d); }
      if (fr == 0) {
        atomicAdd(&ssum[m*16 + g*4 + j], s);
        atomicAdd(&ssq[m*16 + g*4 + j], s2);
      }
    }
    #pragma unroll
    for (int pm = 0; pm < 2; ++pm) {
      unsigned lo = pk2(acc[m][pm][0], acc[m][pm][1]);
      unsigned hi = pk2(acc[m][pm][2], acc[m][pm][3]);
      unsigned plo = (unsigned)__shfl_xor((int)lo, 16, 64);
      unsigned phi = (unsigned)__shfl_xor((int)hi, 16, 64);
      if ((g & 1) == 0) {
        size_t unit = (size_t)(m*2 + (g>>1)) * P_ + pbase + w*32 + pm*16 + fr;
        Y0g[unit] = make_uint4(lo, hi, plo, phi);
      }
    }
  }
  __syncthreads();
  if (tid < 64) { atomicAdd(&sumg[rep + tid], ssum[tid]); atomicAdd(&sqg[rep + tid], ssq[tid]); }
}

__global__ __launch_bounds__(256) void l1_mfma(
    const uint4* __restrict__ Y0g,
    const float* __restrict__ W1, const float* __restrict__ b1,
    const float* __restrict__ sc0, const float* __restrict__ sh0,
    uint4* __restrict__ Y1g, float* __restrict__ sumg, float* __restrict__ sqg)
{
  __shared__ uint4 Wl[8*64];       // 8 KB
  __shared__ float scl[64], shl[64], bl[64];
  __shared__ float ssum[64], ssq[64];

  const int tid = threadIdx.x;
  const int bid0 = blockIdx.x;
  const int rep = (bid0 & 7) << 9;
  const int bid = (bid0 & 7) * ((int)gridDim.x >> 3) + (bid0 >> 3);
  const int pbase = bid * 128;

  if (tid < 64) {
    scl[tid] = sc0[tid]; shl[tid] = sh0[tid];
    bl[tid] = b1 ? b1[tid] : 0.f;
    ssum[tid] = 0.f; ssq[tid] = 0.f;
  }
  for (int u = tid; u < 8*64; u += 256) {
    int kc = u >> 6, o = u & 63;
    const float* wp = W1 + o*64 + kc*8;
    float4 wa = *(const float4*)wp;
    float4 wb = *(const float4*)(wp + 4);
    Wl[u] = make_uint4(pk2(wa.x, wa.y), pk2(wa.z, wa.w), pk2(wb.x, wb.y), pk2(wb.z, wb.w));
  }
  __syncthreads();

  const int lane = tid & 63, w = tid >> 6, g = lane >> 4, fr = lane & 15;

  bfrag xv[2][2];
  #pragma unroll
  for (int kk = 0; kk < 2; ++kk) {
    const int kc = kk*4 + g;
    float4 sa = *(const float4*)&scl[kc*8];
    float4 sb = *(const float4*)&scl[kc*8 + 4];
    float4 ha = *(const float4*)&shl[kc*8];
    float4 hb = *(const float4*)&shl[kc*8 + 4];
    #pragma unroll
    for (int pm = 0; pm < 2; ++pm) {
      uint4 yv = Y0g[(size_t)kc * P_ + pbase + w*32 + pm*16 + fr];
      unsigned r0 = pk2(fmaxf(fmaf(sa.x, b2f(yv.x),       ha.x), 0.f),
                        fmaxf(fmaf(sa.y, b2f(yv.x >> 16), ha.y), 0.f));
      unsigned r1 = pk2(fmaxf(fmaf(sa.z, b2f(yv.y),       ha.z), 0.f),
                        fmaxf(fmaf(sa.w, b2f(yv.y >> 16), ha.w), 0.f));
      unsigned r2 = pk2(fmaxf(fmaf(sb.x, b2f(yv.z),       hb.x), 0.f),
                        fmaxf(fmaf(sb.y, b2f(yv.z >> 16), hb.y), 0.f));
      unsigned r3 = pk2(fmaxf(fmaf(sb.z, b2f(yv.w),       hb.z), 0.f),
                        fmaxf(fmaf(sb.w, b2f(yv.w >> 16), hb.w), 0.f));
      uint4 uu = make_uint4(r0, r1, r2, r3);
      xv[kk][pm] = *(bfrag*)&uu;
    }
  }

  f32x4 acc[4][2];
  #pragma unroll
  for (int m = 0; m < 4; ++m)
    #pragma unroll
    for (int j = 0; j < 4; ++j) {
      float v = bl[m*16 + g*4 + j];
      acc[m][0][j] = v; acc[m][1][j] = v;
    }
  #pragma unroll
  for (int kk = 0; kk < 2; ++kk) {
    const int kc = kk*4 + g;
    bfrag a[4];
    #pragma unroll
    for (int m = 0; m < 4; ++m) { uint4 u = Wl[kc*64 + m*16 + fr]; a[m] = *(bfrag*)&u; }
    #pragma unroll
    for (int m = 0; m < 4; ++m)
      #pragma unroll
      for (int pm = 0; pm < 2; ++pm)
        acc[m][pm] = __builtin_amdgcn_mfma_f32_16x16x32_bf16(a[m], xv[kk][pm], acc[m][pm], 0, 0, 0);
  }

  #pragma unroll
  for (int m = 0; m < 4; ++m) {
    #pragma unroll
    for (int j = 0; j < 4; ++j) {
      float v0 = acc[m][0][j], v1 = acc[m][1][j];
      float s = v0 + v1, s2 = v0*v0 + v1*v1;
      #pragma unroll
      for (int d = 1; d < 16; d <<= 1) { s += __shfl_xor(s, d); s2 += __shfl_xor(s2, d); }
      if (fr == 0) {
        atomicAdd(&ssum[m*16 + g*4 + j], s);
        atomicAdd(&ssq[m*16 + g*4 + j], s2);
      }
    }
    #pragma unroll
    for (int pm = 0; pm < 2; ++pm) {
      unsigned lo = pk2(acc[m][pm][0], acc[m][pm][1]);
      unsigned hi = pk2(acc[m][pm][2], acc[m][pm][3]);
      unsigned plo = (unsigned)__shfl_xor((int)lo, 16, 64);
      unsigned phi = (unsigned)__shfl_xor((int)hi, 16, 64);
      if ((g & 1) == 0) {
        size_t unit = (size_t)(m*2 + (g>>1)) * P_ + pbase + w*32 + pm*16 + fr;
        Y1g[unit] = make_uint4(lo, hi, plo, phi);
      }
    }
  }
  __syncthreads();
  if (tid < 64) { atomicAdd(&sumg[rep + tid], ssum[tid]); atomicAdd(&sqg[rep + tid], ssq[tid]); }
}

__global__ __launch_bounds__(256) void l2_mfma(
    const uint4* __restrict__ Y1g,
    const float* __restrict__ W2, const float* __restrict__ b2,
    const float* __restrict__ sc1, const float* __restrict__ sh1,
    float* __restrict__ mxg, float* __restrict__ mng,
    float* __restrict__ sumg, float* __restrict__ sqg)
{
  __shared__ uint4 Wl[8*128];      // 16 KB
  __shared__ float scl[64], shl[64], bl[128];
  __shared__ float ssum[128], ssq[128];

  const int tid = threadIdx.x;
  const int bid0 = blockIdx.x;
  const int rep = (bid0 & 7) << 9;
  const int bid = (bid0 & 7) * ((int)gridDim.x >> 3) + (bid0 >> 3);
  const int pbase = bid * 128;
  const int q0 = bid * 4;

  if (tid < 64) { scl[tid] = sc1[tid]; shl[tid] = sh1[tid]; }
  if (tid < 128) { bl[tid] = b2 ? b2[tid] : 0.f; ssum[tid] = 0.f; ssq[tid] = 0.f; }
  for (int u = tid; u < 8*128; u += 256) {
    int kc = u >> 7, o = u & 127;
    const float* wp = W2 + o*64 + kc*8;
    float4 wa = *(const float4*)wp;
    float4 wb = *(const float4*)(wp + 4);
    Wl[u] = make_uint4(pk2(wa.x, wa.y), pk2(wa.z, wa.w), pk2(wb.x, wb.y), pk2(wb.z, wb.w));
  }
  __syncthreads();

  const int lane = tid & 63, w = tid >> 6, g = lane >> 4, fr = lane & 15;

  bfrag ax[2][2];
  #pragma unroll
  for (int kk = 0; kk < 2; ++kk) {
    const int kc = kk*4 + g;
    float4 sa = *(const float4*)&scl[kc*8];
    float4 sb = *(const float4*)&scl[kc*8 + 4];
    float4 ha = *(const float4*)&shl[kc*8];
    float4 hb = *(const float4*)&shl[kc*8 + 4];
    #pragma unroll
    for (int pm = 0; pm < 2; ++pm) {
      uint4 yv = Y1g[(size_t)kc * P_ + pbase + w*32 + pm*16 + fr];
      unsigned r0 = pk2(fmaxf(fmaf(sa.x, b2f(yv.x),       ha.x), 0.f),
                        fmaxf(fmaf(sa.y, b2f(yv.x >> 16), ha.y), 0.f));
      unsigned r1 = pk2(fmaxf(fmaf(sa.z, b2f(yv.y),       ha.z), 0.f),
                        fmaxf(fmaf(sa.w, b2f(yv.y >> 16), ha.w), 0.f));
      unsigned r2 = pk2(fmaxf(fmaf(sb.x, b2f(yv.z),       hb.x), 0.f),
                        fmaxf(fmaf(sb.y, b2f(yv.z >> 16), hb.y), 0.f));
      unsigned r3 = pk2(fmaxf(fmaf(sb.z, b2f(yv.w),       hb.z), 0.f),
                        fmaxf(fmaf(sb.w, b2f(yv.w >> 16), hb.w), 0.f));
      uint4 uu = make_uint4(r0, r1, r2, r3);
      ax[kk][pm] = *(bfrag*)&uu;
    }
  }

  f32x4 acc[2][8];
  #pragma unroll
  for (int cn = 0; cn < 8; ++cn) {
    float v = bl[cn*16 + fr];
    #pragma unroll
    for (int j = 0; j < 4; ++j) { acc[0][cn][j] = v; acc[1][cn][j] = v; }
  }
  #pragma unroll
  for (int kk = 0; kk < 2; ++kk) {
    const int kc = kk*4 + g;
    #pragma unroll
    for (int cn = 0; cn < 8; ++cn) {
      uint4 u = Wl[kc*128 + cn*16 + fr];
      bfrag bw = *(bfrag*)&u;
      acc[0][cn] = __builtin_amdgcn_mfma_f32_16x16x32_bf16(ax[kk][0], bw, acc[0][cn], 0, 0, 0);
      acc[1][cn] = __builtin_amdgcn_mfma_f32_16x16x32_bf16(ax[kk][1], bw, acc[1][cn], 0, 0, 0);
    }
  }

  #pragma unroll
  for (int cn = 0; cn < 8; ++cn) {
    float mx = -3.0e38f, mn = 3.0e38f, s = 0.f, s2 = 0.f;
    #pragma unroll
    for (int pm = 0; pm < 2; ++pm)
      #pragma unroll
      for (int j = 0; j < 4; ++j) {
        float v = acc[pm][cn][j];
        mx = fmaxf(mx, v); mn = fminf(mn, v);
        s += v; s2 += v*v;
      }
    #pragma unroll
    for (int d = 16; d < 64; d <<= 1) {
      mx = fmaxf(mx, __shfl_xor(mx, d));
      mn = fminf(mn, __shfl_xor(mn, d));
      s  += __shfl_xor(s, d);
      s2 += __shfl_xor(s2, d);
    }
    if (g == 0) {
      int o = cn*16 + fr;
      size_t q = q0 + w;
      mxg[q*128 + o] = mx;
      mng[q*128 + o] = mn;
      atomicAdd(&ssum[o], s);
      atomicAdd(&ssq[o], s2);
    }
  }
  __syncthreads();
  if (tid < 128) { atomicAdd(&sumg[rep + tid], ssum[tid]); atomicAdd(&sqg[rep + tid], ssq[tid]); }
}

// ---------------------------------------------------------------------------
// BN finalize: sum 8 per-XCD replicas of (sum, sumsq) -> (scale, shift).
// ---------------------------------------------------------------------------
__global__ void finalize_kernel(
    const float* __restrict__ sum, const float* __restrict__ sq,
    const float* __restrict__ g, const float* __restrict__ bt,
    float* __restrict__ sc, float* __restrict__ sh, int C)
{
  int c = threadIdx.x;
  if (c < C) {
    float s = 0.f, s2 = 0.f;
    #pragma unroll
    for (int r = 0; r < 8; ++r) { s += sum[r*512 + c]; s2 += sq[r*512 + c]; }
    const float inv = 1.0f / (float)P_;
    float mu = s * inv;
    float var = s2 * inv - mu * mu;
    var = fmaxf(var, 0.f);
    float rr = 1.0f / sqrtf(var + EPS_);
    float gg = g ? g[c] : 1.0f;
    float bb = bt ? bt[c] : 0.0f;
    float sv = gg * rr;
    sc[c] = sv;
    sh[c] = bb - mu * sv;
  }
}

// ---------------------------------------------------------------------------
// Epilogue: BN2 + ReLU + maxpool (affine commutes with max; min covers
// negative scale), write f32 features.
// ---------------------------------------------------------------------------
__global__ __launch_bounds__(256) void out_kernel(
    const float* __restrict__ mxg, const float* __restrict__ mng,
    const float* __restrict__ sc2, const float* __restrict__ sh2,
    float* __restrict__ out)
{
  int i = blockIdx.x * 256 + threadIdx.x;
  int o = i & 127;
  float a = sc2[o];
  float v = (a >= 0.f) ? mxg[i] : mng[i];
  float z = fmaxf(fmaf(a, v, sh2[o]), 0.f);
  out[(size_t)PQ_ * 3 + i] = z;
}

// ---------------------------------------------------------------------------
extern "C" void kernel_launch(void* const* d_in, const int* in_sizes, int n_in,
                              void* d_out, int out_size, void* d_ws, size_t ws_size,
                              hipStream_t stream)
{
  int i_xyz=-1, i_feat=-1, i_fps=-1, i_w0=-1, i_w1=-1, i_w2=-1;
  for (int i = 0; i < n_in; ++i) {
    switch (in_sizes[i]) {
      case 196608:  i_xyz = i; break;
      case 4194304: i_feat = i; break;
      case 16384:   i_fps = i; break;
      case 4288:    i_w0 = i; break;
      case 4096:    i_w1 = i; break;
      case 8192:    i_w2 = i; break;
      default: break;
    }
  }
  if (i_xyz < 0 || i_feat < 0 || i_fps < 0 || i_w0 < 0 || i_w1 < 0 || i_w2 < 0) return;

  const float* xyz  = (const float*)d_in[i_xyz];
  const float* feat = (const float*)d_in[i_feat];
  const int*   fpsr = (const int*)d_in[i_fps];
  const float* W0 = (const float*)d_in[i_w0];
  const float* W1 = (const float*)d_in[i_w1];
  const float* W2 = (const float*)d_in[i_w2];

  bool canon = (n_in >= 15 && i_xyz==0 && i_feat==1 && i_fps==2 && i_w0==3 &&
                i_w1==7 && i_w2==11 &&
                in_sizes[4]==64 && in_sizes[5]==64 && in_sizes[6]==64 &&
                in_sizes[8]==64 && in_sizes[9]==64 && in_sizes[10]==64 &&
                in_sizes[12]==128 && in_sizes[13]==128 && in_sizes[14]==128);
  const float* b0 = canon ? (const float*)d_in[4]  : nullptr;
  const float* g0 = canon ? (const float*)d_in[5]  : nullptr;
  const float* bt0= canon ? (const float*)d_in[6]  : nullptr;
  const float* b1 = canon ? (const float*)d_in[8]  : nullptr;
  const float* g1 = canon ? (const float*)d_in[9]  : nullptr;
  const float* bt1= canon ? (const float*)d_in[10] : nullptr;
  const float* b2 = canon ? (const float*)d_in[12] : nullptr;
  const float* g2 = canon ? (const float*)d_in[13] : nullptr;
  const float* bt2= canon ? (const float*)d_in[14] : nullptr;

  float* out = (float*)d_out;
  char* ws = (char*)d_ws;
  if (ws_size < WS_NEEDED) return;

  int* idxw = (int*)(ws + OFF_IDX);
  uint4* Y0 = (uint4*)(ws + OFF_Y0);
  uint4* Y1 = (uint4*)(ws + OFF_Y1);
  float* mxg = (float*)(ws + OFF_MX);
  float* mng = (float*)(ws + OFF_MN);
  float* st  = (float*)(ws + OFF_STATS);   // 8 replicas x 512 f32
  float* fin = (float*)(ws + OFF_FIN);
  int* fpsc  = (int*)(ws + OFF_FPSC);
  float4* pxyzw = (float4*)(ws + OFF_PXYZW);

  hipMemsetAsync(st, 0, 16384, stream);

  fps_canon_kernel<<<(PQ_+255)/256, 256, 0, stream>>>(fpsr, fpsc);
  prep_kernel<<<(B_*N_)/256, 256, 0, stream>>>(xyz, pxyzw);

  knn_kernel<<<PQ_/2, 256, 0, stream>>>(pxyzw, fpsc, idxw, out);

  l0_mfma<<<P_/128, 256, 0, stream>>>(xyz, feat, fpsc, idxw, W0, b0, Y0, st + 0, st + 64);
  finalize_kernel<<<1, 64, 0, stream>>>(st + 0, st + 64, g0, bt0, fin + 0, fin + 64, 64);

  l1_mfma<<<P_/128, 256, 0, stream>>>(Y0, W1, b1, fin + 0, fin + 64, Y1, st + 128, st + 192);
  finalize_kernel<<<1, 64, 0, stream>>>(st + 128, st + 192, g1, bt1, fin + 128, fin + 192, 64);

  l2_mfma<<<P_/128, 256, 0, stream>>>(Y1, W2, b2, fin + 128, fin + 192, mxg, mng, st + 256, st + 384);
  finalize_kernel<<<1, 128, 0, stream>>>(st + 256, st + 384, g2, bt2, fin + 256, fin + 384, 128);

  out_kernel<<<(PQ_*128)/256, 256, 0, stream>>>(mxg, mng, fin + 256, fin + 384, out);
}

// Round 14
// 229.205 us; speedup vs baseline: 1.0587x; 1.0587x over previous
//
#include <hip/hip_runtime.h>
#include <stdint.h>

// Problem constants
#define B_   16
#define N_   4096
#define S_   1024
#define K_   32
#define CIN_ 64
#define P_   524288      // B*S*K points through the MLP
#define PQ_  16384       // B*S queries
#define EPS_ 1e-5f

// Workspace layout (bytes)
#define SZ_IDX    ((size_t)P_ * 4)            // knn indices, int32
#define SZ_Y      ((size_t)P_ * 64 * 2)       // 64ch x P bf16 (subtiled units)
#define SZ_MX     ((size_t)PQ_ * 128 * 4)     // per-(q,ch) f32
#define OFF_IDX   ((size_t)0)
#define OFF_Y0    (OFF_IDX + SZ_IDX)
#define OFF_Y1    (OFF_Y0 + SZ_Y)
#define OFF_MX    (OFF_Y1 + SZ_Y)
#define OFF_MN    (OFF_MX + SZ_MX)
#define OFF_STATS (OFF_MN + SZ_MX)            // 8 replicas x 512 f32 (16 KB, zeroed)
#define OFF_FPSC  (OFF_STATS + 16384)         // canonical fps, 16384 int32
#define OFF_PXYZW (OFF_FPSC + (size_t)PQ_ * 4)  // B*N float4 (x,y,z,|x|^2)
#define WS_NEEDED (OFF_PXYZW + (size_t)B_ * N_ * 16)

typedef unsigned short u16;
typedef short bfrag __attribute__((ext_vector_type(8)));   // 8 bf16 (4 VGPRs)
typedef float f32x4 __attribute__((ext_vector_type(4)));

__device__ __forceinline__ float b2f(unsigned v) {
  return __uint_as_float((v & 0xffffu) << 16);
}
__device__ __forceinline__ u16 f2b(float f) {
  unsigned u = __float_as_uint(f);
  unsigned r = (u + 0x7fffu + ((u >> 16) & 1u)) >> 16;  // RNE
  return (u16)r;
}
__device__ __forceinline__ unsigned pk2(float a, float b) {
  return (unsigned)f2b(a) | ((unsigned)f2b(b) << 16);
}

// BN finalize helper (bit-identical to the old finalize_kernel arithmetic):
// raw replica sums (stride 512) -> (scale, shift) for channel c.
__device__ __forceinline__ void bn_fin(
    const float* __restrict__ sum, const float* __restrict__ sq, int c,
    const float* __restrict__ g, const float* __restrict__ bt,
    float& sc, float& sh)
{
  float s = 0.f, s2 = 0.f;
  #pragma unroll
  for (int r = 0; r < 8; ++r) { s += sum[r*512 + c]; s2 += sq[r*512 + c]; }
  const float inv = 1.0f / (float)P_;
  float mu = s * inv;
  float var = s2 * inv - mu * mu;
  var = fmaxf(var, 0.f);
  float rr = 1.0f / sqrtf(var + EPS_);
  float gg = g ? g[c] : 1.0f;
  float bb = bt ? bt[c] : 0.0f;
  float sv = gg * rr;
  sc = sv;
  sh = bb - mu * sv;
}

// ---------------------------------------------------------------------------
// prep + fps canon merged: all 256 blocks pack (x,y,z,|x|^2); blocks 0..63
// also canonicalize fps (int64 vs int32 storage) -> int32, clamped.
// |x|^2 uses the EXACT reference op ordering, f32, no FMA.
// ---------------------------------------------------------------------------
__global__ __launch_bounds__(256) void prep_kernel(
    const float* __restrict__ xyz, float4* __restrict__ pxyzw,
    const int* __restrict__ fpsraw, int* __restrict__ fpsc)
{
  const int tid = threadIdx.x;
  int i = blockIdx.x * 256 + tid;   // 0 .. B*N-1
  float x0 = xyz[i*3+0], x1 = xyz[i*3+1], x2 = xyz[i*3+2];
  float s2 = __fadd_rn(__fadd_rn(__fmul_rn(x0,x0), __fmul_rn(x1,x1)), __fmul_rn(x2,x2));
  pxyzw[i] = make_float4(x0, x1, x2, s2);

  if (blockIdx.x < 64) {
    __shared__ int is64;
    if (tid == 0) is64 = 1;
    __syncthreads();
    if (tid < 64) {
      if (fpsraw[2 * tid + 1] != 0) atomicAnd(&is64, 0);
    }
    __syncthreads();
    int j = blockIdx.x * 256 + tid;
    int src = is64 ? (2 * j) : j;
    int v = fpsraw[src];
    fpsc[j] = (v & 0xFFF);
  }
}

// ---------------------------------------------------------------------------
// KNN (round-12 version): exact 32 smallest (d, idx) via histogram
// radix-select. float4 input; register bin cache; wave-0 serial scan;
// pass 2 rare plain LDS atomics; wave-0 refine with (d, idx) tie-break.
// ---------------------------------------------------------------------------
#define NBIN 2048
#define CAND_CAP 512

__global__ __launch_bounds__(256) void knn_kernel(
    const float4* __restrict__ pxyzw, const int* __restrict__ fps,
    int* __restrict__ idxout, float* __restrict__ out_xyz)
{
  __shared__ unsigned hist[NBIN];      // 8 KB
  __shared__ float cd[CAND_CAP];       // 2 KB
  __shared__ int   ci_[CAND_CAP];      // 2 KB
  __shared__ int   sel[K_];
  __shared__ int   sCnt, sCand, sT;

  const int q   = blockIdx.x;
  const int b   = q >> 10;
  const int tid = threadIdx.x;
  const float4* xb4 = pxyzw + (size_t)b * N_;
  const int ctr = fps[q];
  const float4 cv = xb4[ctr];
  const float cx = cv.x, cy = cv.y, cz = cv.z, s1 = cv.w;

  if (tid == 0) {
    out_xyz[(size_t)q*3+0] = cx;
    out_xyz[(size_t)q*3+1] = cy;
    out_xyz[(size_t)q*3+2] = cz;
    sCnt = 0; sCand = 0;
  }
  {
    uint4* hz = (uint4*)hist;
    hz[tid]       = make_uint4(0,0,0,0);
    hz[tid + 256] = make_uint4(0,0,0,0);
  }
  __syncthreads();

  // pass 1: distances -> registers; bins -> packed registers + histogram.
  float dreg[16];
  unsigned bpk[8];
  #pragma unroll
  for (int it = 0; it < 16; ++it) {
    int n = it * 256 + tid;
    float4 v = xb4[n];
    float dt = __fadd_rn(__fadd_rn(__fmul_rn(cx,v.x), __fmul_rn(cy,v.y)), __fmul_rn(cz,v.z));
    float d  = __fsub_rn(__fadd_rn(s1, v.w), __fmul_rn(2.0f, dt));
    dreg[it] = d;
    int bin = (int)(d * 128.0f);
    bin = bin > (NBIN-1) ? (NBIN-1) : bin;
    bin = bin < 0 ? 0 : bin;
    if (it & 1) bpk[it >> 1] |= (unsigned)bin << 16;
    else        bpk[it >> 1]  = (unsigned)bin;
    atomicAdd(&hist[bin], 1u);
  }
  __syncthreads();

  // scan: wave 0 walks 64 bins at a time until cumulative reaches K
  const int lane = tid & 63, wid = tid >> 6;
  if (wid == 0) {
    int cum = 0, base = 0, found = 0;
    while (!found && base < NBIN) {
      int h = (int)hist[base + lane];
      int pre = h;
      #pragma unroll
      for (int off = 1; off < 64; off <<= 1) {
        int v = __shfl_up(pre, off, 64);
        if (lane >= off) pre += v;
      }
      int tot = __shfl(pre, 63, 64);
      bool cross = (cum + pre >= K_) && (cum + pre - h < K_);
      unsigned long long mm = __ballot(cross);
      if (mm) {
        if (lane == 0) sT = base + (int)(__ffsll((long long)mm) - 1);
        found = 1;
      }
      cum += tot;
      base += 64;
    }
  }
  __syncthreads();
  const int T = sT;

  // pass 2: rare hits -> plain LDS atomics
  #pragma unroll
  for (int it = 0; it < 16; ++it) {
    int bin = (int)((bpk[it >> 1] >> ((it & 1) * 16)) & 0xFFFFu);
    if (bin <= T) {
      int n = it * 256 + tid;
      if (bin < T) {
        int s = atomicAdd(&sCnt, 1);
        if (s < K_) sel[s] = n;
      } else {
        int s = atomicAdd(&sCand, 1);
        if (s < CAND_CAP) { cd[s] = dreg[it]; ci_[s] = n; }
      }
    }
  }
  __syncthreads();

  // refine: wave 0 only (lane owns j == lane mod 64), (d, idx) tie-break
  if (wid == 0) {
    int m = sCnt; m = m > K_ ? K_ : m;
    int cc = sCand; cc = cc > CAND_CAP ? CAND_CAP : cc;
    const int r = K_ - m;
    for (int it = 0; it < r; ++it) {
      float bd = 3.0e38f; int bi = 0x7fffffff;
      for (int j = lane; j < cc; j += 64) {
        float dv = cd[j]; int iv = ci_[j];
        if (dv < bd || (dv == bd && iv < bi)) { bd = dv; bi = iv; }
      }
      #pragma unroll
      for (int off = 32; off > 0; off >>= 1) {
        float od = __shfl_down(bd, off, 64);
        int   oi = __shfl_down(bi, off, 64);
        if (od < bd || (od == bd && oi < bi)) { bd = od; bi = oi; }
      }
      int win = __shfl(bi, 0, 64);
      if (lane == 0) sel[m + it] = win & 0xFFF;
      for (int j = lane; j < cc; j += 64) if (ci_[j] == win) cd[j] = 3.0e38f;
    }
  }
  __syncthreads();
  if (tid < K_) idxout[(size_t)q * K_ + tid] = sel[tid] & 0xFFF;
}

// ===========================================================================
// MFMA MLP layers. Fragment mapping (m89/m91):
//   A(M=16,K=32): lane holds A[row=lane&15][k=(lane>>4)*8+i]
//   B(K=32,N=16): lane holds B[k=(lane>>4)*8+i][col=lane&15]
//   D(M=16,N=16): lane holds D[row=(lane>>4)*4+j][col=lane&15]
// Paired 16B Y stores via shfl_xor(16); 8 per-XCD stats replicas.
// BN finalize is folded into each consumer (bn_fin at block start).
// ===========================================================================

__global__ __launch_bounds__(256) void l0_mfma(
    const float* __restrict__ xyz, const float* __restrict__ feat,
    const int* __restrict__ fps, const int* __restrict__ idxin,
    const float* __restrict__ W0, const float* __restrict__ b0,
    uint4* __restrict__ Y0g, float* __restrict__ sumg, float* __restrict__ sqg)
{
  __shared__ uint4 Wl[12*64];      // 12 KB
  __shared__ float bl[64];
  __shared__ float ssum[64], ssq[64];

  const int tid = threadIdx.x;
  const int bid0 = blockIdx.x;
  const int rep = (bid0 & 7) << 9;
  const int bid = (bid0 & 7) * ((int)gridDim.x >> 3) + (bid0 >> 3);
  const int pbase = bid * 128;
  const int q0 = bid * 4;
  const int b = bid >> 8;

  if (tid < 64) { bl[tid] = b0 ? b0[tid] : 0.f; ssum[tid] = 0.f; ssq[tid] = 0.f; }
  for (int u = tid; u < 12*64; u += 256) {
    int kc = u >> 6, o = u & 63;
    unsigned pk[4];
    #pragma unroll
    for (int hh = 0; hh < 4; ++hh) {
      int c0 = kc*8 + hh*2, c1 = c0 + 1;
      float v0 = (c0 < 64) ? W0[o*67 + 3 + c0] : (c0 < 67 ? W0[o*67 + (c0-64)] : 0.f);
      float v1 = (c1 < 64) ? W0[o*67 + 3 + c1] : (c1 < 67 ? W0[o*67 + (c1-64)] : 0.f);
      pk[hh] = pk2(v0, v1);
    }
    Wl[u] = make_uint4(pk[0], pk[1], pk[2], pk[3]);
  }

  const int lane = tid & 63, w = tid >> 6, g = lane >> 4, fr = lane & 15;
  const float* xb = xyz + (size_t)b * N_ * 3;
  const float* fbase = feat + (size_t)b * N_ * 64;

  int pidx[2];
  const int ct = fps[q0 + w] & 0xFFF;
  #pragma unroll
  for (int pm = 0; pm < 2; ++pm)
    pidx[pm] = idxin[pbase + w*32 + pm*16 + fr] & 0xFFF;

  bfrag xv[3][2];
  #pragma unroll
  for (int kk = 0; kk < 3; ++kk) {
    const int kc = kk*4 + g;
    #pragma unroll
    for (int pm = 0; pm < 2; ++pm) {
      uint4 uu;
      if (kc < 8) {
        const float* fp = fbase + pidx[pm]*64 + kc*8;
        float4 fa = *(const float4*)fp;
        float4 fb2 = *(const float4*)(fp + 4);
        uu = make_uint4(pk2(fa.x, fa.y), pk2(fa.z, fa.w),
                        pk2(fb2.x, fb2.y), pk2(fb2.z, fb2.w));
      } else if (kc == 8) {
        int n = pidx[pm];
        float dx = xb[n*3+0] - xb[ct*3+0];
        float dy = xb[n*3+1] - xb[ct*3+1];
        float dz = xb[n*3+2] - xb[ct*3+2];
        uu = make_uint4(pk2(dx, dy), (unsigned)f2b(dz), 0u, 0u);
      } else {
        uu = make_uint4(0u, 0u, 0u, 0u);
      }
      xv[kk][pm] = *(bfrag*)&uu;
    }
  }
  __syncthreads();

  f32x4 acc[4][2];
  #pragma unroll
  for (int m = 0; m < 4; ++m)
    #pragma unroll
    for (int j = 0; j < 4; ++j) {
      float v = bl[m*16 + g*4 + j];
      acc[m][0][j] = v; acc[m][1][j] = v;
    }
  #pragma unroll
  for (int kk = 0; kk < 3; ++kk) {
    const int kc = kk*4 + g;
    bfrag a[4];
    #pragma unroll
    for (int m = 0; m < 4; ++m) { uint4 u = Wl[kc*64 + m*16 + fr]; a[m] = *(bfrag*)&u; }
    #pragma unroll
    for (int m = 0; m < 4; ++m)
      #pragma unroll
      for (int pm = 0; pm < 2; ++pm)
        acc[m][pm] = __builtin_amdgcn_mfma_f32_16x16x32_bf16(a[m], xv[kk][pm], acc[m][pm], 0, 0, 0);
  }

  #pragma unroll
  for (int m = 0; m < 4; ++m) {
    #pragma unroll
    for (int j = 0; j < 4; ++j) {
      float v0 = acc[m][0][j], v1 = acc[m][1][j];
      float s = v0 + v1, s2 = v0*v0 + v1*v1;
      #pragma unroll
      for (int d = 1; d < 16; d <<= 1) { s += __shfl_xor(s, d); s2 += __shfl_xor(s2, d); }
      if (fr == 0) {
        atomicAdd(&ssum[m*16 + g*4 + j], s);
        atomicAdd(&ssq[m*16 + g*4 + j], s2);
      }
    }
    #pragma unroll
    for (int pm = 0; pm < 2; ++pm) {
      unsigned lo = pk2(acc[m][pm][0], acc[m][pm][1]);
      unsigned hi = pk2(acc[m][pm][2], acc[m][pm][3]);
      unsigned plo = (unsigned)__shfl_xor((int)lo, 16, 64);
      unsigned phi = (unsigned)__shfl_xor((int)hi, 16, 64);
      if ((g & 1) == 0) {
        size_t unit = (size_t)(m*2 + (g>>1)) * P_ + pbase + w*32 + pm*16 + fr;
        Y0g[unit] = make_uint4(lo, hi, plo, phi);
      }
    }
  }
  __syncthreads();
  if (tid < 64) { atomicAdd(&sumg[rep + tid], ssum[tid]); atomicAdd(&sqg[rep + tid], ssq[tid]); }
}

__global__ __launch_bounds__(256) void l1_mfma(
    const uint4* __restrict__ Y0g,
    const float* __restrict__ W1, const float* __restrict__ b1,
    const float* __restrict__ g0, const float* __restrict__ bt0,
    const float* __restrict__ sum0, const float* __restrict__ sq0,
    uint4* __restrict__ Y1g, float* __restrict__ sumg, float* __restrict__ sqg)
{
  __shared__ uint4 Wl[8*64];       // 8 KB
  __shared__ float scl[64], shl[64], bl[64];
  __shared__ float ssum[64], ssq[64];

  const int tid = threadIdx.x;
  const int bid0 = blockIdx.x;
  const int rep = (bid0 & 7) << 9;
  const int bid = (bid0 & 7) * ((int)gridDim.x >> 3) + (bid0 >> 3);
  const int pbase = bid * 128;

  if (tid < 64) {
    float sc, sh;
    bn_fin(sum0, sq0, tid, g0, bt0, sc, sh);
    scl[tid] = sc; shl[tid] = sh;
    bl[tid] = b1 ? b1[tid] : 0.f;
    ssum[tid] = 0.f; ssq[tid] = 0.f;
  }
  for (int u = tid; u < 8*64; u += 256) {
    int kc = u >> 6, o = u & 63;
    const float* wp = W1 + o*64 + kc*8;
    float4 wa = *(const float4*)wp;
    float4 wb = *(const float4*)(wp + 4);
    Wl[u] = make_uint4(pk2(wa.x, wa.y), pk2(wa.z, wa.w), pk2(wb.x, wb.y), pk2(wb.z, wb.w));
  }
  __syncthreads();

  const int lane = tid & 63, w = tid >> 6, g = lane >> 4, fr = lane & 15;

  bfrag xv[2][2];
  #pragma unroll
  for (int kk = 0; kk < 2; ++kk) {
    const int kc = kk*4 + g;
    float4 sa = *(const float4*)&scl[kc*8];
    float4 sb = *(const float4*)&scl[kc*8 + 4];
    float4 ha = *(const float4*)&shl[kc*8];
    float4 hb = *(const float4*)&shl[kc*8 + 4];
    #pragma unroll
    for (int pm = 0; pm < 2; ++pm) {
      uint4 yv = Y0g[(size_t)kc * P_ + pbase + w*32 + pm*16 + fr];
      unsigned r0 = pk2(fmaxf(fmaf(sa.x, b2f(yv.x),       ha.x), 0.f),
                        fmaxf(fmaf(sa.y, b2f(yv.x >> 16), ha.y), 0.f));
      unsigned r1 = pk2(fmaxf(fmaf(sa.z, b2f(yv.y),       ha.z), 0.f),
                        fmaxf(fmaf(sa.w, b2f(yv.y >> 16), ha.w), 0.f));
      unsigned r2 = pk2(fmaxf(fmaf(sb.x, b2f(yv.z),       hb.x), 0.f),
                        fmaxf(fmaf(sb.y, b2f(yv.z >> 16), hb.y), 0.f));
      unsigned r3 = pk2(fmaxf(fmaf(sb.z, b2f(yv.w),       hb.z), 0.f),
                        fmaxf(fmaf(sb.w, b2f(yv.w >> 16), hb.w), 0.f));
      uint4 uu = make_uint4(r0, r1, r2, r3);
      xv[kk][pm] = *(bfrag*)&uu;
    }
  }

  f32x4 acc[4][2];
  #pragma unroll
  for (int m = 0; m < 4; ++m)
    #pragma unroll
    for (int j = 0; j < 4; ++j) {
      float v = bl[m*16 + g*4 + j];
      acc[m][0][j] = v; acc[m][1][j] = v;
    }
  #pragma unroll
  for (int kk = 0; kk < 2; ++kk) {
    const int kc = kk*4 + g;
    bfrag a[4];
    #pragma unroll
    for (int m = 0; m < 4; ++m) { uint4 u = Wl[kc*64 + m*16 + fr]; a[m] = *(bfrag*)&u; }
    #pragma unroll
    for (int m = 0; m < 4; ++m)
      #pragma unroll
      for (int pm = 0; pm < 2; ++pm)
        acc[m][pm] = __builtin_amdgcn_mfma_f32_16x16x32_bf16(a[m], xv[kk][pm], acc[m][pm], 0, 0, 0);
  }

  #pragma unroll
  for (int m = 0; m < 4; ++m) {
    #pragma unroll
    for (int j = 0; j < 4; ++j) {
      float v0 = acc[m][0][j], v1 = acc[m][1][j];
      float s = v0 + v1, s2 = v0*v0 + v1*v1;
      #pragma unroll
      for (int d = 1; d < 16; d <<= 1) { s += __shfl_xor(s, d); s2 += __shfl_xor(s2, d); }
      if (fr == 0) {
        atomicAdd(&ssum[m*16 + g*4 + j], s);
        atomicAdd(&ssq[m*16 + g*4 + j], s2);
      }
    }
    #pragma unroll
    for (int pm = 0; pm < 2; ++pm) {
      unsigned lo = pk2(acc[m][pm][0], acc[m][pm][1]);
      unsigned hi = pk2(acc[m][pm][2], acc[m][pm][3]);
      unsigned plo = (unsigned)__shfl_xor((int)lo, 16, 64);
      unsigned phi = (unsigned)__shfl_xor((int)hi, 16, 64);
      if ((g & 1) == 0) {
        size_t unit = (size_t)(m*2 + (g>>1)) * P_ + pbase + w*32 + pm*16 + fr;
        Y1g[unit] = make_uint4(lo, hi, plo, phi);
      }
    }
  }
  __syncthreads();
  if (tid < 64) { atomicAdd(&sumg[rep + tid], ssum[tid]); atomicAdd(&sqg[rep + tid], ssq[tid]); }
}

__global__ __launch_bounds__(256) void l2_mfma(
    const uint4* __restrict__ Y1g,
    const float* __restrict__ W2, const float* __restrict__ b2,
    const float* __restrict__ g1, const float* __restrict__ bt1,
    const float* __restrict__ sum1, const float* __restrict__ sq1,
    float* __restrict__ mxg, float* __restrict__ mng,
    float* __restrict__ sumg, float* __restrict__ sqg)
{
  __shared__ uint4 Wl[8*128];      // 16 KB
  __shared__ float scl[64], shl[64], bl[128];
  __shared__ float ssum[128], ssq[128];

  const int tid = threadIdx.x;
  const int bid0 = blockIdx.x;
  const int rep = (bid0 & 7) << 9;
  const int bid = (bid0 & 7) * ((int)gridDim.x >> 3) + (bid0 >> 3);
  const int pbase = bid * 128;
  const int q0 = bid * 4;

  if (tid < 64) {
    float sc, sh;
    bn_fin(sum1, sq1, tid, g1, bt1, sc, sh);
    scl[tid] = sc; shl[tid] = sh;
  }
  if (tid < 128) { bl[tid] = b2 ? b2[tid] : 0.f; ssum[tid] = 0.f; ssq[tid] = 0.f; }
  for (int u = tid; u < 8*128; u += 256) {
    int kc = u >> 7, o = u & 127;
    const float* wp = W2 + o*64 + kc*8;
    float4 wa = *(const float4*)wp;
    float4 wb = *(const float4*)(wp + 4);
    Wl[u] = make_uint4(pk2(wa.x, wa.y), pk2(wa.z, wa.w), pk2(wb.x, wb.y), pk2(wb.z, wb.w));
  }
  __syncthreads();

  const int lane = tid & 63, w = tid >> 6, g = lane >> 4, fr = lane & 15;

  bfrag ax[2][2];
  #pragma unroll
  for (int kk = 0; kk < 2; ++kk) {
    const int kc = kk*4 + g;
    float4 sa = *(const float4*)&scl[kc*8];
    float4 sb = *(const float4*)&scl[kc*8 + 4];
    float4 ha = *(const float4*)&shl[kc*8];
    float4 hb = *(const float4*)&shl[kc*8 + 4];
    #pragma unroll
    for (int pm = 0; pm < 2; ++pm) {
      uint4 yv = Y1g[(size_t)kc * P_ + pbase + w*32 + pm*16 + fr];
      unsigned r0 = pk2(fmaxf(fmaf(sa.x, b2f(yv.x),       ha.x), 0.f),
                        fmaxf(fmaf(sa.y, b2f(yv.x >> 16), ha.y), 0.f));
      unsigned r1 = pk2(fmaxf(fmaf(sa.z, b2f(yv.y),       ha.z), 0.f),
                        fmaxf(fmaf(sa.w, b2f(yv.y >> 16), ha.w), 0.f));
      unsigned r2 = pk2(fmaxf(fmaf(sb.x, b2f(yv.z),       hb.x), 0.f),
                        fmaxf(fmaf(sb.y, b2f(yv.z >> 16), hb.y), 0.f));
      unsigned r3 = pk2(fmaxf(fmaf(sb.z, b2f(yv.w),       hb.z), 0.f),
                        fmaxf(fmaf(sb.w, b2f(yv.w >> 16), hb.w), 0.f));
      uint4 uu = make_uint4(r0, r1, r2, r3);
      ax[kk][pm] = *(bfrag*)&uu;
    }
  }

  f32x4 acc[2][8];
  #pragma unroll
  for (int cn = 0; cn < 8; ++cn) {
    float v = bl[cn*16 + fr];
    #pragma unroll
    for (int j = 0; j < 4; ++j) { acc[0][cn][j] = v; acc[1][cn][j] = v; }
  }
  #pragma unroll
  for (int kk = 0; kk < 2; ++kk) {
    const int kc = kk*4 + g;
    #pragma unroll
    for (int cn = 0; cn < 8; ++cn) {
      uint4 u = Wl[kc*128 + cn*16 + fr];
      bfrag bw = *(bfrag*)&u;
      acc[0][cn] = __builtin_amdgcn_mfma_f32_16x16x32_bf16(ax[kk][0], bw, acc[0][cn], 0, 0, 0);
      acc[1][cn] = __builtin_amdgcn_mfma_f32_16x16x32_bf16(ax[kk][1], bw, acc[1][cn], 0, 0, 0);
    }
  }

  #pragma unroll
  for (int cn = 0; cn < 8; ++cn) {
    float mx = -3.0e38f, mn = 3.0e38f, s = 0.f, s2 = 0.f;
    #pragma unroll
    for (int pm = 0; pm < 2; ++pm)
      #pragma unroll
      for (int j = 0; j < 4; ++j) {
        float v = acc[pm][cn][j];
        mx = fmaxf(mx, v); mn = fminf(mn, v);
        s += v; s2 += v*v;
      }
    #pragma unroll
    for (int d = 16; d < 64; d <<= 1) {
      mx = fmaxf(mx, __shfl_xor(mx, d));
      mn = fminf(mn, __shfl_xor(mn, d));
      s  += __shfl_xor(s, d);
      s2 += __shfl_xor(s2, d);
    }
    if (g == 0) {
      int o = cn*16 + fr;
      size_t q = q0 + w;
      mxg[q*128 + o] = mx;
      mng[q*128 + o] = mn;
      atomicAdd(&ssum[o], s);
      atomicAdd(&ssq[o], s2);
    }
  }
  __syncthreads();
  if (tid < 128) { atomicAdd(&sumg[rep + tid], ssum[tid]); atomicAdd(&sqg[rep + tid], ssq[tid]); }
}

// ---------------------------------------------------------------------------
// Epilogue: BN2 finalize (folded) + ReLU + maxpool (affine commutes with max;
// min covers negative scale), write f32 features. Grid-strided, 2048 blocks.
// ---------------------------------------------------------------------------
__global__ __launch_bounds__(256) void out_kernel(
    const float* __restrict__ mxg, const float* __restrict__ mng,
    const float* __restrict__ g2, const float* __restrict__ bt2,
    const float* __restrict__ sum2, const float* __restrict__ sq2,
    float* __restrict__ out)
{
  __shared__ float scl[128], shl[128];
  const int tid = threadIdx.x;
  if (tid < 128) {
    float sc, sh;
    bn_fin(sum2, sq2, tid, g2, bt2, sc, sh);
    scl[tid] = sc; shl[tid] = sh;
  }
  __syncthreads();

  const int base = blockIdx.x * 1024;
  #pragma unroll
  for (int t = 0; t < 4; ++t) {
    int i = base + t * 256 + tid;
    int o = i & 127;
    float a = scl[o];
    float v = (a >= 0.f) ? mxg[i] : mng[i];
    float z = fmaxf(fmaf(a, v, shl[o]), 0.f);
    out[(size_t)PQ_ * 3 + i] = z;
  }
}

// ---------------------------------------------------------------------------
extern "C" void kernel_launch(void* const* d_in, const int* in_sizes, int n_in,
                              void* d_out, int out_size, void* d_ws, size_t ws_size,
                              hipStream_t stream)
{
  int i_xyz=-1, i_feat=-1, i_fps=-1, i_w0=-1, i_w1=-1, i_w2=-1;
  for (int i = 0; i < n_in; ++i) {
    switch (in_sizes[i]) {
      case 196608:  i_xyz = i; break;
      case 4194304: i_feat = i; break;
      case 16384:   i_fps = i; break;
      case 4288:    i_w0 = i; break;
      case 4096:    i_w1 = i; break;
      case 8192:    i_w2 = i; break;
      default: break;
    }
  }
  if (i_xyz < 0 || i_feat < 0 || i_fps < 0 || i_w0 < 0 || i_w1 < 0 || i_w2 < 0) return;

  const float* xyz  = (const float*)d_in[i_xyz];
  const float* feat = (const float*)d_in[i_feat];
  const int*   fpsr = (const int*)d_in[i_fps];
  const float* W0 = (const float*)d_in[i_w0];
  const float* W1 = (const float*)d_in[i_w1];
  const float* W2 = (const float*)d_in[i_w2];

  bool canon = (n_in >= 15 && i_xyz==0 && i_feat==1 && i_fps==2 && i_w0==3 &&
                i_w1==7 && i_w2==11 &&
                in_sizes[4]==64 && in_sizes[5]==64 && in_sizes[6]==64 &&
                in_sizes[8]==64 && in_sizes[9]==64 && in_sizes[10]==64 &&
                in_sizes[12]==128 && in_sizes[13]==128 && in_sizes[14]==128);
  const float* b0 = canon ? (const float*)d_in[4]  : nullptr;
  const float* g0 = canon ? (const float*)d_in[5]  : nullptr;
  const float* bt0= canon ? (const float*)d_in[6]  : nullptr;
  const float* b1 = canon ? (const float*)d_in[8]  : nullptr;
  const float* g1 = canon ? (const float*)d_in[9]  : nullptr;
  const float* bt1= canon ? (const float*)d_in[10] : nullptr;
  const float* b2 = canon ? (const float*)d_in[12] : nullptr;
  const float* g2 = canon ? (const float*)d_in[13] : nullptr;
  const float* bt2= canon ? (const float*)d_in[14] : nullptr;

  float* out = (float*)d_out;
  char* ws = (char*)d_ws;
  if (ws_size < WS_NEEDED) return;

  int* idxw = (int*)(ws + OFF_IDX);
  uint4* Y0 = (uint4*)(ws + OFF_Y0);
  uint4* Y1 = (uint4*)(ws + OFF_Y1);
  float* mxg = (float*)(ws + OFF_MX);
  float* mng = (float*)(ws + OFF_MN);
  float* st  = (float*)(ws + OFF_STATS);   // 8 replicas x 512 f32
  int* fpsc  = (int*)(ws + OFF_FPSC);
  float4* pxyzw = (float4*)(ws + OFF_PXYZW);

  hipMemsetAsync(st, 0, 16384, stream);

  prep_kernel<<<(B_*N_)/256, 256, 0, stream>>>(xyz, pxyzw, fpsr, fpsc);

  knn_kernel<<<PQ_, 256, 0, stream>>>(pxyzw, fpsc, idxw, out);

  l0_mfma<<<P_/128, 256, 0, stream>>>(xyz, feat, fpsc, idxw, W0, b0, Y0, st + 0, st + 64);

  l1_mfma<<<P_/128, 256, 0, stream>>>(Y0, W1, b1, g0, bt0, st + 0, st + 64,
                                      Y1, st + 128, st + 192);

  l2_mfma<<<P_/128, 256, 0, stream>>>(Y1, W2, b2, g1, bt1, st + 128, st + 192,
                                      mxg, mng, st + 256, st + 384);

  out_kernel<<<2048, 256, 0, stream>>>(mxg, mng, g2, bt2, st + 256, st + 384, out);
}